// Round 1
// baseline (516.566 us; speedup 1.0000x reference)
//
#include <hip/hip_runtime.h>
#include <hip/hip_bf16.h>
#include <stdint.h>

// Problem: B=32, C=1024, H=W=32, S=1024, nh=1, hd=1024.
// out[b,o,s] = vsum[b,s] * sum_t Wp[o,t]*attn[b,t,s] + b_proj[o] + x[b,o,s]
// attn[t,s]  = softmax_s( (q_t . k_s)/32 ),  q=Wq X, k=Wk X
// vsum[b,s]  = sum_c (sum_o Wv[o,c]) x[b,c,s]

typedef __attribute__((ext_vector_type(8))) short short8;
typedef __attribute__((ext_vector_type(4))) float f32x4;

__device__ __forceinline__ short f2b(float f) {
    __hip_bfloat16 h = __float2bfloat16(f);
    return *reinterpret_cast<short*>(&h);
}
__device__ __forceinline__ float b2f(short s) {
    __hip_bfloat16 h;
    *reinterpret_cast<short*>(&h) = s;
    return __bfloat162float(h);
}

#define GLOAD16(g, l) __builtin_amdgcn_global_load_lds(                        \
    (const __attribute__((address_space(1))) unsigned int*)(g),                \
    (__attribute__((address_space(3))) unsigned int*)(l), 16, 0, 0)

// ---- wvsum[c] = sum_o w_qkv[2048+o][c]
__global__ void k_wvsum(const float* __restrict__ wqkv, float* __restrict__ wvsum) {
    int c = blockIdx.x * 256 + threadIdx.x;
    float s = 0.f;
    const float* p = wqkv + (size_t)2048 * 1024 + c;
    for (int o = 0; o < 1024; ++o) s += p[(size_t)o * 1024];
    wvsum[c] = s;
}

// ---- f32 -> bf16 convert (n multiple of 1024)
__global__ void k_cvt(const float* __restrict__ in, short* __restrict__ out) {
    int i = (blockIdx.x * 256 + threadIdx.x) * 4;
    #pragma unroll
    for (int j = 0; j < 4; ++j) out[i + j] = f2b(in[i + j]);
}

// ---- xT[b][s][c] = bf16(x[b][c][s]); vsum[b][s] += sum_c wvsum[c]*x[b][c][s]
__global__ void k_xpose(const float* __restrict__ x, const float* __restrict__ wvsum,
                        short* __restrict__ xT, float* __restrict__ vsum) {
    __shared__ float tile[32][33];
    __shared__ float ps[8][32];
    int b = blockIdx.z;
    int s0 = blockIdx.x * 32, c0 = blockIdx.y * 32;
    int tx = threadIdx.x, ty = threadIdx.y;
    const float* xb = x + ((size_t)b << 20);
    float p = 0.f;
    #pragma unroll
    for (int i = 0; i < 4; ++i) {
        int cl = ty + i * 8;
        float v = xb[(size_t)(c0 + cl) * 1024 + s0 + tx];
        tile[cl][tx] = v;
        p += v * wvsum[c0 + cl];
    }
    ps[ty][tx] = p;
    __syncthreads();
    short* xTb = xT + ((size_t)b << 20);
    #pragma unroll
    for (int i = 0; i < 4; ++i) {
        int sl = ty + i * 8;
        xTb[(size_t)(s0 + sl) * 1024 + c0 + tx] = f2b(tile[tx][sl]);
    }
    if (ty == 0) {
        float s = 0.f;
        #pragma unroll
        for (int i = 0; i < 8; ++i) s += ps[i][tx];
        atomicAdd(&vsum[b * 1024 + s0 + tx], s);
    }
}

// ---- generic 128x128x(K) bf16 GEMM, D[i,j] = sum_k A[i,k]*Bt[j,k]
// MODE 0: store bf16 D to O (ldo)                         [QK-gen, writes qkT]
// MODE 1: E=exp(D/32) -> bf16 O; Z[col] += column sums    [logits+exp]
// MODE 2: out = D*vsum[col] + bias[row] + xres -> f32 O   [proj+epilogue]
template <int MODE>
__global__ void k_gemm(const short* __restrict__ A0, size_t strideA, int lda,
                       const short* __restrict__ B0, size_t strideB, int ldb,
                       void* __restrict__ O0, size_t strideO, int ldo,
                       float* __restrict__ Z,
                       const float* __restrict__ vsum,
                       const float* __restrict__ bias,
                       const float* __restrict__ xres,
                       int K) {
    __shared__ short As[128 * 32];
    __shared__ short Bs[128 * 32];
    int z = blockIdx.z;
    int m0 = blockIdx.y * 128, n0 = blockIdx.x * 128;
    int tid = threadIdx.x;
    int wid = tid >> 6, l = tid & 63;
    int wm = wid >> 1, wn = wid & 1;
    int lr = l & 15, lg = l >> 4;

    const short* A = A0 + (size_t)z * strideA;
    const short* Bt = B0 + (size_t)z * strideB;

    f32x4 acc[4][4] = {};

    int e = tid * 8;        // 8 bf16 (16B) per thread per staging call
    int r0 = e >> 5;        // row within first 64
    int c0e = e & 31;
    const short* ga = A + (size_t)(m0 + r0) * lda + c0e;
    const short* gb = Bt + (size_t)(n0 + r0) * ldb + c0e;

    for (int kk = 0; kk < K; kk += 32) {
        GLOAD16(ga,            &As[wid * 512]);
        GLOAD16(ga + 64 * lda, &As[2048 + wid * 512]);
        GLOAD16(gb,            &Bs[wid * 512]);
        GLOAD16(gb + 64 * ldb, &Bs[2048 + wid * 512]);
        ga += 32; gb += 32;
        __syncthreads();
        short8 af[4], bf[4];
        #pragma unroll
        for (int mi = 0; mi < 4; ++mi)
            af[mi] = *(const short8*)&As[(wm * 64 + mi * 16 + lr) * 32 + lg * 8];
        #pragma unroll
        for (int ni = 0; ni < 4; ++ni)
            bf[ni] = *(const short8*)&Bs[(wn * 64 + ni * 16 + lr) * 32 + lg * 8];
        #pragma unroll
        for (int mi = 0; mi < 4; ++mi)
            #pragma unroll
            for (int ni = 0; ni < 4; ++ni)
                acc[mi][ni] = __builtin_amdgcn_mfma_f32_16x16x32_bf16(
                    af[mi], bf[ni], acc[mi][ni], 0, 0, 0);
        __syncthreads();
    }

    int rb = m0 + wm * 64;
    int cb = n0 + wn * 64;
    if (MODE == 0) {
        short* O = (short*)O0 + (size_t)z * strideO;
        #pragma unroll
        for (int mi = 0; mi < 4; ++mi)
            #pragma unroll
            for (int ni = 0; ni < 4; ++ni)
                #pragma unroll
                for (int r = 0; r < 4; ++r)
                    O[(size_t)(rb + mi * 16 + lg * 4 + r) * ldo + cb + ni * 16 + lr] =
                        f2b(acc[mi][ni][r]);
    } else if (MODE == 1) {
        short* O = (short*)O0 + (size_t)z * strideO;
        float* Zb = Z + z * 1024;
        #pragma unroll
        for (int ni = 0; ni < 4; ++ni) {
            float zs = 0.f;
            #pragma unroll
            for (int mi = 0; mi < 4; ++mi)
                #pragma unroll
                for (int r = 0; r < 4; ++r) {
                    float ev = __expf(acc[mi][ni][r] * 0.03125f);
                    O[(size_t)(rb + mi * 16 + lg * 4 + r) * ldo + cb + ni * 16 + lr] = f2b(ev);
                    zs += ev;
                }
            zs += __shfl_xor(zs, 16);
            zs += __shfl_xor(zs, 32);
            if (l < 16) atomicAdd(&Zb[cb + ni * 16 + l], zs);
        }
    } else {
        float* O = (float*)O0 + (size_t)z * strideO;
        const float* xr = xres + (size_t)z * strideO;
        #pragma unroll
        for (int mi = 0; mi < 4; ++mi)
            #pragma unroll
            for (int ni = 0; ni < 4; ++ni)
                #pragma unroll
                for (int r = 0; r < 4; ++r) {
                    int row = rb + mi * 16 + lg * 4 + r;
                    int col = cb + ni * 16 + lr;
                    float v = acc[mi][ni][r] * vsum[z * 1024 + col] + bias[row] +
                              xr[(size_t)row * ldo + col];
                    O[(size_t)row * ldo + col] = v;
                }
    }
}

__global__ void k_invz(float* Z) {
    int i = blockIdx.x * 256 + threadIdx.x;
    Z[i] = 1.0f / Z[i];
}

// attnT *= invZ[b*1024 + t] (t = fastest dim)
__global__ void k_scale(short* __restrict__ attnT, const float* __restrict__ invZ) {
    size_t i8 = ((size_t)blockIdx.x * 256 + threadIdx.x) * 8;
    short8 v = *(short8*)&attnT[i8];
    int b = (int)(i8 >> 20);
    int t = (int)(i8 & 1023);
    const float* iz = invZ + b * 1024 + t;
    #pragma unroll
    for (int j = 0; j < 8; ++j) v[j] = f2b(b2f(v[j]) * iz[j]);
    *(short8*)&attnT[i8] = v;
}

extern "C" void kernel_launch(void* const* d_in, const int* in_sizes, int n_in,
                              void* d_out, int out_size, void* d_ws, size_t ws_size,
                              hipStream_t stream) {
    const float* x     = (const float*)d_in[0];
    const float* wqkv  = (const float*)d_in[1];
    const float* wproj = (const float*)d_in[2];
    const float* bproj = (const float*)d_in[3];
    float* out = (float*)d_out;

    char* ws = (char*)d_ws;
    size_t off = 0;
    auto alloc = [&](size_t bytes) {
        void* p = ws + off;
        off += (bytes + 255) & ~(size_t)255;
        return p;
    };
    float* wvsum = (float*)alloc(1024 * 4);
    short* wqk_b = (short*)alloc((size_t)2048 * 1024 * 2);
    short* wp_b  = (short*)alloc((size_t)1024 * 1024 * 2);
    short* xT    = (short*)alloc((size_t)32 * 1024 * 1024 * 2);
    short* qkT   = (short*)alloc((size_t)32 * 1024 * 2048 * 2);
    short* attnT = (short*)alloc((size_t)32 * 1024 * 1024 * 2);
    float* vsum  = (float*)alloc(32 * 1024 * 4);
    float* Zbuf  = (float*)alloc(32 * 1024 * 4);

    hipMemsetAsync(vsum, 0, 32 * 1024 * 4, stream);
    hipMemsetAsync(Zbuf, 0, 32 * 1024 * 4, stream);

    k_wvsum<<<4, 256, 0, stream>>>(wqkv, wvsum);
    k_cvt<<<2048, 256, 0, stream>>>(wqkv, wqk_b);   // 2048*1024 elems
    k_cvt<<<1024, 256, 0, stream>>>(wproj, wp_b);   // 1024*1024 elems
    k_xpose<<<dim3(32, 32, 32), dim3(32, 8), 0, stream>>>(x, wvsum, xT, vsum);

    // qkT[b][s][o] = sum_c xT[s,c] * wqk[o,c]   (M=1024, N=2048, K=1024)
    k_gemm<0><<<dim3(16, 8, 32), 256, 0, stream>>>(
        xT, (size_t)1048576, 1024, wqk_b, 0, 1024,
        qkT, (size_t)2097152, 2048, nullptr, nullptr, nullptr, nullptr, 1024);

    // E[b][s][t] = exp(sum_c kT[s,c]*qT[t,c] / 32); Z[b][t] += col sums
    k_gemm<1><<<dim3(8, 8, 32), 256, 0, stream>>>(
        qkT + 1024, (size_t)2097152, 2048, qkT, (size_t)2097152, 2048,
        attnT, (size_t)1048576, 1024, Zbuf, nullptr, nullptr, nullptr, 1024);

    k_invz<<<128, 256, 0, stream>>>(Zbuf);
    k_scale<<<16384, 256, 0, stream>>>(attnT, Zbuf);

    // out[b][o][s] = (sum_t Wp[o,t]*attn[s,t]) * vsum[s] + bias[o] + x[b][o][s]
    k_gemm<2><<<dim3(8, 8, 32), 256, 0, stream>>>(
        wp_b, 0, 1024, attnT, (size_t)1048576, 1024,
        out, (size_t)1048576, 1024, nullptr, vsum, bproj, x, 1024);
}

// Round 2
// 510.592 us; speedup vs baseline: 1.0117x; 1.0117x over previous
//
#include <hip/hip_runtime.h>
#include <hip/hip_bf16.h>
#include <stdint.h>

// Problem: B=32, C=1024, H=W=32, S=1024, nh=1, hd=1024.
// out[b,o,s] = vsum[b,s] * sum_t Wp[o,t]*attn[b,t,s] + b_proj[o] + x[b,o,s]
// attn[t,s]  = softmax_s( (q_t . k_s)/32 ),  q=Wq X, k=Wk X
// vsum[b,s]  = sum_c (sum_o Wv[o,c]) x[b,c,s]

typedef __attribute__((ext_vector_type(8))) short short8;
typedef __attribute__((ext_vector_type(4))) float f32x4;

__device__ __forceinline__ short f2b(float f) {
    __hip_bfloat16 h = __float2bfloat16(f);
    return *reinterpret_cast<short*>(&h);
}
__device__ __forceinline__ float b2f(short s) {
    __hip_bfloat16 h;
    *reinterpret_cast<short*>(&h) = s;
    return __bfloat162float(h);
}

#define GLOAD16(gp, lp) __builtin_amdgcn_global_load_lds(                      \
    (const __attribute__((address_space(1))) unsigned int*)(gp),               \
    (__attribute__((address_space(3))) unsigned int*)(lp), 16, 0, 0)

// ---- wvsum[c] = sum_o w_qkv[2048+o][c]
__global__ void k_wvsum(const float* __restrict__ wqkv, float* __restrict__ wvsum) {
    int c = blockIdx.x * 256 + threadIdx.x;
    float s = 0.f;
    const float* p = wqkv + (size_t)2048 * 1024 + c;
    for (int o = 0; o < 1024; ++o) s += p[(size_t)o * 1024];
    wvsum[c] = s;
}

// ---- f32 -> bf16 convert (n multiple of 1024)
__global__ void k_cvt(const float* __restrict__ in, short* __restrict__ out) {
    int i = (blockIdx.x * 256 + threadIdx.x) * 4;
    #pragma unroll
    for (int j = 0; j < 4; ++j) out[i + j] = f2b(in[i + j]);
}

// ---- xT[b][s][c] = bf16(x[b][c][s]); vsum[b][s] += sum_c wvsum[c]*x[b][c][s]
__global__ void k_xpose(const float* __restrict__ x, const float* __restrict__ wvsum,
                        short* __restrict__ xT, float* __restrict__ vsum) {
    __shared__ float tile[32][33];
    __shared__ float ps[8][32];
    int b = blockIdx.z;
    int s0 = blockIdx.x * 32, c0 = blockIdx.y * 32;
    int tx = threadIdx.x, ty = threadIdx.y;
    const float* xb = x + ((size_t)b << 20);
    float p = 0.f;
    #pragma unroll
    for (int i = 0; i < 4; ++i) {
        int cl = ty + i * 8;
        float v = xb[(size_t)(c0 + cl) * 1024 + s0 + tx];
        tile[cl][tx] = v;
        p += v * wvsum[c0 + cl];
    }
    ps[ty][tx] = p;
    __syncthreads();
    short* xTb = xT + ((size_t)b << 20);
    #pragma unroll
    for (int i = 0; i < 4; ++i) {
        int sl = ty + i * 8;
        xTb[(size_t)(s0 + sl) * 1024 + c0 + tx] = f2b(tile[tx][sl]);
    }
    if (ty == 0) {
        float s = 0.f;
        #pragma unroll
        for (int i = 0; i < 8; ++i) s += ps[i][tx];
        atomicAdd(&vsum[b * 1024 + s0 + tx], s);
    }
}

// ---- 256x256-tile bf16 GEMM, K=1024 fixed. D[i,j] = sum_k A[i,k]*Bt[j,k]
// 8 waves (2m x 4n), per-wave C 128x64, BK=32, 4-deep LDS ring, counted vmcnt.
// MODE 0: store bf16 D                      MODE 1: E=exp(D/32), Z[col]+=sums
// MODE 2: out = D*vsum[col]+bias[row]+xres (f32)
template <int MODE, int TM, int TN>
__global__ __launch_bounds__(512, 2)
void k_gemm(const short* __restrict__ A0, size_t strideA, int lda,
            const short* __restrict__ B0, size_t strideB, int ldb,
            void* __restrict__ O0, size_t strideO, int ldo,
            float* __restrict__ Z,
            const float* __restrict__ vsum,
            const float* __restrict__ bias,
            const float* __restrict__ xres) {
    __shared__ __align__(16) short As[4][8192];   // 4 slots x [256][32]
    __shared__ __align__(16) short Bs[4][8192];

    constexpr int TPB = TM * TN;        // tiles per batch
    constexpr int CPX = TPB * 4;        // wgids per XCD chunk (nwg = TPB*32)
    int wg = blockIdx.x;
    int swz = (wg & 7) * CPX + (wg >> 3);      // XCD-aware swizzle (nwg%8==0)
    int z = swz / TPB;
    int rz = swz - z * TPB;
    int m0 = (rz / TN) * 256, n0 = (rz % TN) * 256;

    int tid = threadIdx.x;
    int wid = tid >> 6, l = tid & 63;
    int wm = wid >> 2, wn = wid & 3;
    int lr = l & 15, lg = l >> 4;

    const short* A = A0 + (size_t)z * strideA;
    const short* Bt = B0 + (size_t)z * strideB;

    // staging: per-lane pre-swizzled global src (rule #21: linear LDS dest,
    // inverse-swizzled source, swizzled ds_read).  chunk' = chunk ^ ((row>>1)&3)
    int srow = l >> 2;
    int chunk = (l & 3) ^ ((l >> 3) & 3);
    const short* pA0 = A + (size_t)(m0 + wid * 32 + srow) * lda + chunk * 8;
    const short* pA1 = pA0 + (size_t)16 * lda;
    const short* pB0 = Bt + (size_t)(n0 + wid * 32 + srow) * ldb + chunk * 8;
    const short* pB1 = pB0 + (size_t)16 * ldb;
    char* ldA = (char*)&As[0][0] + wid * 2048;
    char* ldB = (char*)&Bs[0][0] + wid * 2048;

    auto STAGE = [&](int slot) {
        GLOAD16(pA0, ldA + slot * 16384);
        GLOAD16(pA1, ldA + slot * 16384 + 1024);
        GLOAD16(pB0, ldB + slot * 16384);
        GLOAD16(pB1, ldB + slot * 16384 + 1024);
        pA0 += 32; pA1 += 32; pB0 += 32; pB1 += 32;
    };

    f32x4 acc[8][4] = {};
    int xr4 = (lg ^ ((lr >> 1) & 3)) * 16;            // swizzled 16B chunk
    int offA = (wm * 128 + lr) * 64 + xr4;
    int offB = (wn * 64 + lr) * 64 + xr4;

    auto COMPUTE = [&](int slot) {
        const char* ab = (const char*)&As[0][0] + slot * 16384 + offA;
        const char* bb = (const char*)&Bs[0][0] + slot * 16384 + offB;
        short8 af[8], bf[4];
        #pragma unroll
        for (int ni = 0; ni < 4; ++ni) bf[ni] = *(const short8*)(bb + ni * 1024);
        #pragma unroll
        for (int mi = 0; mi < 8; ++mi) af[mi] = *(const short8*)(ab + mi * 1024);
        __builtin_amdgcn_s_setprio(1);
        #pragma unroll
        for (int mi = 0; mi < 8; ++mi)
            #pragma unroll
            for (int ni = 0; ni < 4; ++ni)
                acc[mi][ni] = __builtin_amdgcn_mfma_f32_16x16x32_bf16(
                    af[mi], bf[ni], acc[mi][ni], 0, 0, 0);
        __builtin_amdgcn_s_setprio(0);
        // drain reads before next barrier so post-barrier stages can't race them
        asm volatile("s_waitcnt lgkmcnt(0)" ::: "memory");
    };

    // prologue: 3 tiles in flight
    STAGE(0); STAGE(1); STAGE(2);
    for (int t = 0; t < 29; ++t) {
        asm volatile("s_waitcnt vmcnt(8)" ::: "memory");   // tile t landed (all waves via barrier)
        __builtin_amdgcn_s_barrier();
        STAGE((t + 3) & 3);
        COMPUTE(t & 3);
    }
    asm volatile("s_waitcnt vmcnt(8)" ::: "memory");
    __builtin_amdgcn_s_barrier();
    COMPUTE(1);                                            // t=29
    asm volatile("s_waitcnt vmcnt(4)" ::: "memory");
    __builtin_amdgcn_s_barrier();
    COMPUTE(2);                                            // t=30
    asm volatile("s_waitcnt vmcnt(0)" ::: "memory");
    __builtin_amdgcn_s_barrier();
    COMPUTE(3);                                            // t=31

    int rb = m0 + wm * 128, cb = n0 + wn * 64;
    if (MODE == 0) {
        short* O = (short*)O0 + (size_t)z * strideO;
        #pragma unroll
        for (int mi = 0; mi < 8; ++mi)
            #pragma unroll
            for (int ni = 0; ni < 4; ++ni)
                #pragma unroll
                for (int r = 0; r < 4; ++r)
                    O[(size_t)(rb + mi * 16 + lg * 4 + r) * ldo + cb + ni * 16 + lr] =
                        f2b(acc[mi][ni][r]);
    } else if (MODE == 1) {
        short* O = (short*)O0 + (size_t)z * strideO;
        float* Zb = Z + z * 1024;
        #pragma unroll
        for (int ni = 0; ni < 4; ++ni) {
            float zs = 0.f;
            #pragma unroll
            for (int mi = 0; mi < 8; ++mi)
                #pragma unroll
                for (int r = 0; r < 4; ++r) {
                    float ev = __expf(acc[mi][ni][r] * 0.03125f);
                    O[(size_t)(rb + mi * 16 + lg * 4 + r) * ldo + cb + ni * 16 + lr] = f2b(ev);
                    zs += ev;
                }
            zs += __shfl_xor(zs, 16);
            zs += __shfl_xor(zs, 32);
            if (l < 16) atomicAdd(&Zb[cb + ni * 16 + l], zs);
        }
    } else {
        float* O = (float*)O0 + (size_t)z * strideO;
        const float* xr = xres + (size_t)z * strideO;
        #pragma unroll
        for (int mi = 0; mi < 8; ++mi)
            #pragma unroll
            for (int ni = 0; ni < 4; ++ni)
                #pragma unroll
                for (int r = 0; r < 4; ++r) {
                    int row = rb + mi * 16 + lg * 4 + r;
                    int col = cb + ni * 16 + lr;
                    O[(size_t)row * ldo + col] = acc[mi][ni][r] * vsum[z * 1024 + col] +
                                                 bias[row] + xr[(size_t)row * ldo + col];
                }
    }
}

__global__ void k_invz(float* Z) {
    int i = blockIdx.x * 256 + threadIdx.x;
    Z[i] = 1.0f / Z[i];
}

// attnT *= invZ[b*1024 + t] (t = fastest dim)
__global__ void k_scale(short* __restrict__ attnT, const float* __restrict__ invZ) {
    size_t i8 = ((size_t)blockIdx.x * 256 + threadIdx.x) * 8;
    short8 v = *(short8*)&attnT[i8];
    int b = (int)(i8 >> 20);
    int t = (int)(i8 & 1023);
    const float* iz = invZ + b * 1024 + t;
    #pragma unroll
    for (int j = 0; j < 8; ++j) v[j] = f2b(b2f(v[j]) * iz[j]);
    *(short8*)&attnT[i8] = v;
}

extern "C" void kernel_launch(void* const* d_in, const int* in_sizes, int n_in,
                              void* d_out, int out_size, void* d_ws, size_t ws_size,
                              hipStream_t stream) {
    const float* x     = (const float*)d_in[0];
    const float* wqkv  = (const float*)d_in[1];
    const float* wproj = (const float*)d_in[2];
    const float* bproj = (const float*)d_in[3];
    float* out = (float*)d_out;

    char* ws = (char*)d_ws;
    size_t off = 0;
    auto alloc = [&](size_t bytes) {
        void* p = ws + off;
        off += (bytes + 255) & ~(size_t)255;
        return p;
    };
    float* wvsum = (float*)alloc(1024 * 4);
    short* wqk_b = (short*)alloc((size_t)2048 * 1024 * 2);
    short* wp_b  = (short*)alloc((size_t)1024 * 1024 * 2);
    short* xT    = (short*)alloc((size_t)32 * 1024 * 1024 * 2);
    short* qkT   = (short*)alloc((size_t)32 * 1024 * 2048 * 2);
    short* attnT = (short*)alloc((size_t)32 * 1024 * 1024 * 2);
    float* vsum  = (float*)alloc(32 * 1024 * 4);
    float* Zbuf  = (float*)alloc(32 * 1024 * 4);

    hipMemsetAsync(vsum, 0, 32 * 1024 * 4, stream);
    hipMemsetAsync(Zbuf, 0, 32 * 1024 * 4, stream);

    k_wvsum<<<4, 256, 0, stream>>>(wqkv, wvsum);
    k_cvt<<<2048, 256, 0, stream>>>(wqkv, wqk_b);
    k_cvt<<<1024, 256, 0, stream>>>(wproj, wp_b);
    k_xpose<<<dim3(32, 32, 32), dim3(32, 8), 0, stream>>>(x, wvsum, xT, vsum);

    // qkT[b][s][o] = sum_c xT[s,c] * wqk[o,c]   (M=1024, N=2048, K=1024)
    k_gemm<0, 4, 8><<<1024, 512, 0, stream>>>(
        xT, (size_t)1048576, 1024, wqk_b, 0, 1024,
        qkT, (size_t)2097152, 2048, nullptr, nullptr, nullptr, nullptr);

    // E[b][s][t] = exp(sum_c kT[s,c]*qT[t,c] / 32); Z[b][t] += col sums
    k_gemm<1, 4, 4><<<512, 512, 0, stream>>>(
        qkT + 1024, (size_t)2097152, 2048, qkT, (size_t)2097152, 2048,
        attnT, (size_t)1048576, 1024, Zbuf, nullptr, nullptr, nullptr);

    k_invz<<<128, 256, 0, stream>>>(Zbuf);
    k_scale<<<16384, 256, 0, stream>>>(attnT, Zbuf);

    // out[b][o][s] = (sum_t Wp[o,t]*attn[s,t]) * vsum[s] + bias[o] + x[b][o][s]
    k_gemm<2, 4, 4><<<512, 512, 0, stream>>>(
        wp_b, 0, 1024, attnT, (size_t)1048576, 1024,
        out, (size_t)1048576, 1024, nullptr, vsum, bproj, x);
}

// Round 3
// 448.524 us; speedup vs baseline: 1.1517x; 1.1384x over previous
//
#include <hip/hip_runtime.h>
#include <hip/hip_bf16.h>
#include <stdint.h>

// Problem: B=32, C=1024, H=W=32, S=1024, nh=1, hd=1024.
// out[b,o,s] = vsum[b,s] * sum_t Wp[o,t]*attn[b,t,s] + b_proj[o] + x[b,o,s]
// attn[t,s]  = softmax_s( (q_t . k_s)/32 ),  q=Wq X, k=Wk X
// vsum[b,s]  = sum_c (sum_o Wv[o,c]) x[b,c,s]

typedef __attribute__((ext_vector_type(8))) short short8;
typedef __attribute__((ext_vector_type(4))) float f32x4;

__device__ __forceinline__ short f2b(float f) {
    __hip_bfloat16 h = __float2bfloat16(f);
    return *reinterpret_cast<short*>(&h);
}
__device__ __forceinline__ float b2f(short s) {
    __hip_bfloat16 h;
    *reinterpret_cast<short*>(&h) = s;
    return __bfloat162float(h);
}

#define GLOAD16(gp, lp) __builtin_amdgcn_global_load_lds(                      \
    (const __attribute__((address_space(1))) unsigned int*)(gp),               \
    (__attribute__((address_space(3))) unsigned int*)(lp), 16, 0, 0)

#define WAITV4 asm volatile("s_waitcnt vmcnt(4)" ::: "memory")
#define WAITV0 asm volatile("s_waitcnt vmcnt(0)" ::: "memory")
#define WAITL0 asm volatile("s_waitcnt lgkmcnt(0)" ::: "memory")
#define BAR()  { asm volatile("" ::: "memory"); __builtin_amdgcn_s_barrier(); \
                 asm volatile("" ::: "memory"); }

// ---- wvsum[c] = sum_o w_qkv[2048+o][c]
__global__ void k_wvsum(const float* __restrict__ wqkv, float* __restrict__ wvsum) {
    int c = blockIdx.x * 256 + threadIdx.x;
    float s = 0.f;
    const float* p = wqkv + (size_t)2048 * 1024 + c;
    for (int o = 0; o < 1024; ++o) s += p[(size_t)o * 1024];
    wvsum[c] = s;
}

// ---- f32 -> bf16 convert (n multiple of 1024)
__global__ void k_cvt(const float* __restrict__ in, short* __restrict__ out) {
    int i = (blockIdx.x * 256 + threadIdx.x) * 4;
    #pragma unroll
    for (int j = 0; j < 4; ++j) out[i + j] = f2b(in[i + j]);
}

// ---- xT[b][s][c] = bf16(x[b][c][s]); vsum[b][s] += sum_c wvsum[c]*x[b][c][s]
__global__ void k_xpose(const float* __restrict__ x, const float* __restrict__ wvsum,
                        short* __restrict__ xT, float* __restrict__ vsum) {
    __shared__ float tile[32][33];
    __shared__ float ps[8][32];
    int b = blockIdx.z;
    int s0 = blockIdx.x * 32, c0 = blockIdx.y * 32;
    int tx = threadIdx.x, ty = threadIdx.y;
    const float* xb = x + ((size_t)b << 20);
    float p = 0.f;
    #pragma unroll
    for (int i = 0; i < 4; ++i) {
        int cl = ty + i * 8;
        float v = xb[(size_t)(c0 + cl) * 1024 + s0 + tx];
        tile[cl][tx] = v;
        p += v * wvsum[c0 + cl];
    }
    ps[ty][tx] = p;
    __syncthreads();
    short* xTb = xT + ((size_t)b << 20);
    #pragma unroll
    for (int i = 0; i < 4; ++i) {
        int sl = ty + i * 8;
        xTb[(size_t)(s0 + sl) * 1024 + c0 + tx] = f2b(tile[tx][sl]);
    }
    if (ty == 0) {
        float s = 0.f;
        #pragma unroll
        for (int i = 0; i < 8; ++i) s += ps[i][tx];
        atomicAdd(&vsum[b * 1024 + s0 + tx], s);
    }
}

// ---- 256x256-tile bf16 GEMM, K=1024 (16 K-tiles of 64). D[i,j]=sum_k A[i,k]*Bt[j,k]
// 8 waves (2m x 4n), per-wave C 128x64. m201-style 8-phase schedule:
// per K-tile 4 phases {ds_read subtile | stage 1 half-tile | bar | lgkm0 |
// 16 MFMA | bar}, vmcnt(4) only at P4/P8. LDS: 2 K-tile dbuf, chunk^=(row&7).
template <int MODE, int TM, int TN>
__global__ __launch_bounds__(512, 2)
void k_gemm(const short* __restrict__ A0, size_t strideA, int lda,
            const short* __restrict__ B0, size_t strideB, int ldb,
            void* __restrict__ O0, size_t strideO, int ldo,
            float* __restrict__ Z,
            const float* __restrict__ vsum,
            const float* __restrict__ bias,
            const float* __restrict__ xres) {
    __shared__ __align__(16) short As[2 * 256 * 64];   // 64 KB: [buf][256 rows][64 k]
    __shared__ __align__(16) short Bs[2 * 256 * 64];   // 64 KB

    constexpr int TPB = TM * TN;
    constexpr int CPX = TPB * 4;               // (32 batches * TPB) / 8 XCDs
    int wg = blockIdx.x;
    int swz = (wg & 7) * CPX + (wg >> 3);      // bijective: nwg % 8 == 0
    int z = swz / TPB;
    int rz = swz - z * TPB;
    int m0 = (rz / TN) * 256, n0 = (rz % TN) * 256;

    int tid = threadIdx.x;
    int wid = tid >> 6, l = tid & 63;
    int wm = wid >> 2, wn = wid & 3;
    int lr = l & 15, lg = l >> 4;

    const short* A = A0 + (size_t)z * strideA;
    const short* Bt = B0 + (size_t)z * strideB;

    // staging: thread covers tile-row wid*16+q*8+(l>>3); source chunk pre-swizzled
    // (rule #21: linear gload_lds dest + inverse-swizzled source + swizzled read)
    int srow = wid * 16 + (l >> 3);
    int scol = ((l & 7) ^ (l >> 3)) * 8;
    const short* gA = A + (size_t)(m0 + srow) * lda + scol;
    const short* gB = Bt + (size_t)(n0 + srow) * ldb + scol;
    char* const ldsA = (char*)As;
    char* const ldsB = (char*)Bs;
    int sdst = wid * 2048;

    auto SA = [&](int buf, int h, int t) __attribute__((always_inline)) {
        const short* g = gA + (size_t)(h * 128) * lda + t * 64;
        char* d = ldsA + buf * 32768 + h * 16384 + sdst;
        GLOAD16(g, d);
        GLOAD16(g + (size_t)8 * lda, d + 1024);
    };
    auto SB = [&](int buf, int h, int t) __attribute__((always_inline)) {
        const short* g = gB + (size_t)(h * 128) * ldb + t * 64;
        char* d = ldsB + buf * 32768 + h * 16384 + sdst;
        GLOAD16(g, d);
        GLOAD16(g + (size_t)8 * ldb, d + 1024);
    };

    // read-side swizzled 16B-chunk offsets (row&7 == lr&7 for all fragments)
    int cs0 = ((lg) ^ (lr & 7)) * 16;
    int cs1 = ((4 + lg) ^ (lr & 7)) * 16;
    int arow = (wm * 128 + lr) * 128;          // byte offset of A row
    int brow = (wn * 64 + lr) * 128;           // byte offset of B row

    short8 af[8], bf0[4], bf1[4];
    f32x4 acc[8][4] = {};

    auto LDA_ = [&](int buf, int mh) __attribute__((always_inline)) {
        const char* p = ldsA + buf * 32768 + arow + mh * 64 * 128;
        #pragma unroll
        for (int mi = 0; mi < 4; ++mi) {
            af[mi * 2]     = *(const short8*)(p + mi * 2048 + cs0);
            af[mi * 2 + 1] = *(const short8*)(p + mi * 2048 + cs1);
        }
    };
    auto LDB_ = [&](short8* dst, int buf, int nh) __attribute__((always_inline)) {
        const char* p = ldsB + buf * 32768 + brow + nh * 32 * 128;
        #pragma unroll
        for (int ni = 0; ni < 2; ++ni) {
            dst[ni * 2]     = *(const short8*)(p + ni * 2048 + cs0);
            dst[ni * 2 + 1] = *(const short8*)(p + ni * 2048 + cs1);
        }
    };
    auto MMA = [&](int mh, int nh, const short8* bfp) __attribute__((always_inline)) {
        __builtin_amdgcn_s_setprio(1);
        #pragma unroll
        for (int ks = 0; ks < 2; ++ks)
            #pragma unroll
            for (int mi = 0; mi < 4; ++mi)
                #pragma unroll
                for (int ni = 0; ni < 2; ++ni)
                    acc[mh * 4 + mi][nh * 2 + ni] =
                        __builtin_amdgcn_mfma_f32_16x16x32_bf16(
                            af[mi * 2 + ks], bfp[ni * 2 + ks],
                            acc[mh * 4 + mi][nh * 2 + ni], 0, 0, 0);
        __builtin_amdgcn_s_setprio(0);
    };

    // prologue: tile0 all 4 halves + tile1 B halves (6 half-tiles, 12 loads)
    SB(0, 0, 0); SB(0, 1, 0); SA(0, 0, 0); SA(0, 1, 0);
    SB(1, 0, 1); SB(1, 1, 1);
    WAITV4;            // tile0 fully landed (tile1.B may be in flight)
    BAR();

    // main loop: iterations j=0..6 compute tiles 2j (buf0), 2j+1 (buf1)
    for (int j = 0; j < 7; ++j) {
        int t1 = 2 * j + 1, t2 = 2 * j + 2, t3 = 2 * j + 3;
        // P1
        LDA_(0, 0); LDB_(bf0, 0, 0); SA(1, 0, t1);
        BAR(); WAITL0; MMA(0, 0, bf0); BAR();
        // P2
        LDB_(bf1, 0, 1); SA(1, 1, t1);
        BAR(); WAITL0; MMA(0, 1, bf1); BAR();
        // P3
        LDA_(0, 1); SB(0, 0, t2);
        BAR(); WAITL0; MMA(1, 0, bf0); BAR();
        // P4
        SB(0, 1, t2); WAITV4;
        BAR(); MMA(1, 1, bf1); BAR();
        // P5
        LDA_(1, 0); LDB_(bf0, 1, 0); SA(0, 0, t2);
        BAR(); WAITL0; MMA(0, 0, bf0); BAR();
        // P6
        LDB_(bf1, 1, 1); SA(0, 1, t2);
        BAR(); WAITL0; MMA(0, 1, bf1); BAR();
        // P7
        LDA_(1, 1); SB(1, 0, t3);
        BAR(); WAITL0; MMA(1, 0, bf0); BAR();
        // P8
        SB(1, 1, t3); WAITV4;
        BAR(); MMA(1, 1, bf1); BAR();
    }
    // epilogue: tiles 14 (buf0), 15 (buf1); only 15.A left to stage
    LDA_(0, 0); LDB_(bf0, 0, 0); SA(1, 0, 15);
    BAR(); WAITL0; MMA(0, 0, bf0); BAR();
    LDB_(bf1, 0, 1); SA(1, 1, 15);
    BAR(); WAITL0; MMA(0, 1, bf1); BAR();
    LDA_(0, 1);
    BAR(); WAITL0; MMA(1, 0, bf0); BAR();
    WAITV0;
    BAR(); MMA(1, 1, bf1); BAR();
    LDA_(1, 0); LDB_(bf0, 1, 0);
    BAR(); WAITL0; MMA(0, 0, bf0); BAR();
    LDB_(bf1, 1, 1);
    BAR(); WAITL0; MMA(0, 1, bf1); BAR();
    LDA_(1, 1);
    BAR(); WAITL0; MMA(1, 0, bf0); BAR();
    MMA(1, 1, bf1);

    int rb = m0 + wm * 128, cb = n0 + wn * 64;
    if (MODE == 0) {
        short* O = (short*)O0 + (size_t)z * strideO;
        #pragma unroll
        for (int mi = 0; mi < 8; ++mi)
            #pragma unroll
            for (int ni = 0; ni < 4; ++ni)
                #pragma unroll
                for (int r = 0; r < 4; ++r)
                    O[(size_t)(rb + mi * 16 + lg * 4 + r) * ldo + cb + ni * 16 + lr] =
                        f2b(acc[mi][ni][r]);
    } else if (MODE == 1) {
        short* O = (short*)O0 + (size_t)z * strideO;
        float* Zb = Z + z * 1024;
        #pragma unroll
        for (int ni = 0; ni < 4; ++ni) {
            float zs = 0.f;
            #pragma unroll
            for (int mi = 0; mi < 8; ++mi)
                #pragma unroll
                for (int r = 0; r < 4; ++r) {
                    float ev = __expf(acc[mi][ni][r] * 0.03125f);
                    O[(size_t)(rb + mi * 16 + lg * 4 + r) * ldo + cb + ni * 16 + lr] = f2b(ev);
                    zs += ev;
                }
            zs += __shfl_xor(zs, 16);
            zs += __shfl_xor(zs, 32);
            if (l < 16) atomicAdd(&Zb[cb + ni * 16 + l], zs);
        }
    } else {
        float* O = (float*)O0 + (size_t)z * strideO;
        const float* xr = xres + (size_t)z * strideO;
        #pragma unroll
        for (int mi = 0; mi < 8; ++mi)
            #pragma unroll
            for (int ni = 0; ni < 4; ++ni)
                #pragma unroll
                for (int r = 0; r < 4; ++r) {
                    int row = rb + mi * 16 + lg * 4 + r;
                    int col = cb + ni * 16 + lr;
                    O[(size_t)row * ldo + col] = acc[mi][ni][r] * vsum[z * 1024 + col] +
                                                 bias[row] + xr[(size_t)row * ldo + col];
                }
    }
}

__global__ void k_invz(float* Z) {
    int i = blockIdx.x * 256 + threadIdx.x;
    Z[i] = 1.0f / Z[i];
}

// attnT *= invZ[b*1024 + t] (t = fastest dim)
__global__ void k_scale(short* __restrict__ attnT, const float* __restrict__ invZ) {
    size_t i8 = ((size_t)blockIdx.x * 256 + threadIdx.x) * 8;
    short8 v = *(short8*)&attnT[i8];
    int b = (int)(i8 >> 20);
    int t = (int)(i8 & 1023);
    const float* iz = invZ + b * 1024 + t;
    #pragma unroll
    for (int j = 0; j < 8; ++j) v[j] = f2b(b2f(v[j]) * iz[j]);
    *(short8*)&attnT[i8] = v;
}

extern "C" void kernel_launch(void* const* d_in, const int* in_sizes, int n_in,
                              void* d_out, int out_size, void* d_ws, size_t ws_size,
                              hipStream_t stream) {
    const float* x     = (const float*)d_in[0];
    const float* wqkv  = (const float*)d_in[1];
    const float* wproj = (const float*)d_in[2];
    const float* bproj = (const float*)d_in[3];
    float* out = (float*)d_out;

    char* ws = (char*)d_ws;
    size_t off = 0;
    auto alloc = [&](size_t bytes) {
        void* p = ws + off;
        off += (bytes + 255) & ~(size_t)255;
        return p;
    };
    float* wvsum = (float*)alloc(1024 * 4);
    short* wqk_b = (short*)alloc((size_t)2048 * 1024 * 2);
    short* wp_b  = (short*)alloc((size_t)1024 * 1024 * 2);
    short* xT    = (short*)alloc((size_t)32 * 1024 * 1024 * 2);
    short* qkT   = (short*)alloc((size_t)32 * 1024 * 2048 * 2);
    short* attnT = (short*)alloc((size_t)32 * 1024 * 1024 * 2);
    float* vsum  = (float*)alloc(32 * 1024 * 4);
    float* Zbuf  = (float*)alloc(32 * 1024 * 4);

    hipMemsetAsync(vsum, 0, 32 * 1024 * 4, stream);
    hipMemsetAsync(Zbuf, 0, 32 * 1024 * 4, stream);

    k_wvsum<<<4, 256, 0, stream>>>(wqkv, wvsum);
    k_cvt<<<2048, 256, 0, stream>>>(wqkv, wqk_b);
    k_cvt<<<1024, 256, 0, stream>>>(wproj, wp_b);
    k_xpose<<<dim3(32, 32, 32), dim3(32, 8), 0, stream>>>(x, wvsum, xT, vsum);

    // qkT[b][s][o] = sum_c xT[s,c] * wqk[o,c]   (M=1024, N=2048, K=1024)
    k_gemm<0, 4, 8><<<1024, 512, 0, stream>>>(
        xT, (size_t)1048576, 1024, wqk_b, 0, 1024,
        qkT, (size_t)2097152, 2048, nullptr, nullptr, nullptr, nullptr);

    // E[b][s][t] = exp(sum_c kT[s,c]*qT[t,c] / 32); Z[b][t] += col sums
    k_gemm<1, 4, 4><<<512, 512, 0, stream>>>(
        qkT + 1024, (size_t)2097152, 2048, qkT, (size_t)2097152, 2048,
        attnT, (size_t)1048576, 1024, Zbuf, nullptr, nullptr, nullptr);

    k_invz<<<128, 256, 0, stream>>>(Zbuf);
    k_scale<<<16384, 256, 0, stream>>>(attnT, Zbuf);

    // out[b][o][s] = (sum_t Wp[o,t]*attn[s,t]) * vsum[s] + bias[o] + x[b][o][s]
    k_gemm<2, 4, 4><<<512, 512, 0, stream>>>(
        wp_b, 0, 1024, attnT, (size_t)1048576, 1024,
        out, (size_t)1048576, 1024, nullptr, vsum, bproj, x);
}